// Round 13
// baseline (1827.354 us; speedup 1.0000x reference)
//
#include <hip/hip_runtime.h>
#include <hip/hip_fp16.h>
#include <cstdint>
#include <cstddef>

// LSTM 3-layer, H=2048, B=16, T=128, I=128, O=1 (fp32 in/out).
// R13 = R12 with the folded-cvt fixed:
//  - TIME-MAJOR chunk indexing (chunk = t*65536 + blk*256 + tid): per step a
//    block touches a contiguous 8KB span -> coalesced reads AND writes.
//    (R12 was thread-major: 512B-stride 16B stores = 4x write amplification,
//    WRITE_SIZE 16->119MB, scan +27us/layer.)
//  - cvt loads issued AFTER xp (not before the poll): poll's vmcnt(0) no
//    longer drains cold-HBM cvt loads; they drain at the barrier instead,
//    hidden under the xp drain.
// Base: W_hh in LDS (XOR-swizzled); dual flag arrays + 4 replicas; cached h
// consumer loads; xp after af; 4 MFMA chains; parallel fa/fb poll.

typedef __attribute__((ext_vector_type(8))) _Float16 fp16x8;
typedef __attribute__((ext_vector_type(4))) float    f32x4;

#define HDIM  2048
#define GATES 8192
#define BATCH 16
#define TSEQ  128
#define NTOK  2048
#define RED_ST 17
#define HSLOT 128               // fp16 per kblock row: 16 batch x 8 units
#define HSTEP_ELEMS 32768       // fp16 per step slot (64KB)
#define FLAG_STRIDE 16          // ints: 64B per flag line
#define NFLAG_COPY 4
#define FB_OFF (NFLAG_COPY * 256 * FLAG_STRIDE)   // second flag array (ints)
#define W_LDS_BYTES 131072

union HU { _Float16 f; unsigned short u; };

__device__ __forceinline__ float sigmoidf_(float x) { return 1.f / (1.f + __expf(-x)); }
__device__ __forceinline__ float tanhf_(float x) {
    float e2 = __expf(2.f * x);
    return 1.f - 2.f / (e2 + 1.f);
}

// ---------------- fp32 -> fp16 conversion (8 elems/thread) -------------------
__global__ __launch_bounds__(256) void cvt_f32_f16_kernel(const float* __restrict__ in,
                                                          _Float16* __restrict__ out, int n8) {
    int i = blockIdx.x * 256 + threadIdx.x;
    if (i >= n8) return;
    const float4* p = (const float4*)in + (size_t)i * 2;
    float4 a = p[0], b = p[1];
    fp16x8 v;
    v[0] = (_Float16)a.x; v[1] = (_Float16)a.y; v[2] = (_Float16)a.z; v[3] = (_Float16)a.w;
    v[4] = (_Float16)b.x; v[5] = (_Float16)b.y; v[6] = (_Float16)b.z; v[7] = (_Float16)b.w;
    ((fp16x8*)out)[i] = v;
}

// ---------------- x_proj GEMM ------------------------------------------------
// A-source: flat [NTOK][K] fp16 (A) or h slot ring (Ah != nullptr).
// Output: xp[t][b][n] fp32 (n contiguous -> coalesced epilogue stores).
__global__ __launch_bounds__(256) void xproj_gemm_kernel(
        const _Float16* __restrict__ A, const _Float16* __restrict__ Ah,
        const _Float16* __restrict__ W,
        const float* __restrict__ bih, const float* __restrict__ bhh,
        float* __restrict__ xp, int K) {
    __shared__ _Float16 As[128 * 64];
    __shared__ _Float16 Bs[128 * 64];
    const int tid  = threadIdx.x;
    const int lane = tid & 63;
    const int wave = tid >> 6;
    const int n0 = blockIdx.x * 128;
    const int m0 = blockIdx.y * 128;
    const int srow = tid >> 3;
    const int scol = (tid & 7) * 8;
    const int wr = (wave >> 1) * 64;
    const int wc = (wave & 1) * 64;
    const int lr = lane & 15;
    const int lk = (lane >> 4) * 8;

    f32x4 acc[4][4] = {};

    const int nk = K >> 6;
    for (int kt = 0; kt < nk; ++kt) {
        if (kt) __syncthreads();
        const int k0 = kt * 64;
#pragma unroll
        for (int cc = 0; cc < 4; ++cc) {
            const int row = cc * 32 + srow;
            const _Float16* ga;
            if (Ah) {
                const int m = m0 + row, b = m >> 7, tt = m & 127;
                ga = Ah + (size_t)(tt + 1) * HSTEP_ELEMS + (size_t)(k0 + scol) * 16 + b * 8;
            } else {
                ga = A + (size_t)(m0 + row) * K + k0 + scol;
            }
            const _Float16* gb = W + (size_t)(n0 + row) * K + k0 + scol;
            __builtin_amdgcn_global_load_lds(
                (const __attribute__((address_space(1))) void*)ga,
                (__attribute__((address_space(3))) void*)(As + cc * 2048 + wave * 512), 16, 0, 0);
            __builtin_amdgcn_global_load_lds(
                (const __attribute__((address_space(1))) void*)gb,
                (__attribute__((address_space(3))) void*)(Bs + cc * 2048 + wave * 512), 16, 0, 0);
        }
        __syncthreads();
#pragma unroll
        for (int s = 0; s < 2; ++s) {
            fp16x8 af[4], bf[4];
#pragma unroll
            for (int mi = 0; mi < 4; ++mi)
                af[mi] = *(const fp16x8*)(As + (wr + mi * 16 + lr) * 64 + s * 32 + lk);
#pragma unroll
            for (int ni = 0; ni < 4; ++ni)
                bf[ni] = *(const fp16x8*)(Bs + (wc + ni * 16 + lr) * 64 + s * 32 + lk);
#pragma unroll
            for (int mi = 0; mi < 4; ++mi)
#pragma unroll
                for (int ni = 0; ni < 4; ++ni)
                    acc[mi][ni] = __builtin_amdgcn_mfma_f32_16x16x32_f16(
                        af[mi], bf[ni], acc[mi][ni], 0, 0, 0);
        }
    }
    const int rb = (lane >> 4) * 4;
#pragma unroll
    for (int ni = 0; ni < 4; ++ni) {
        const int n = n0 + wc + ni * 16 + lr;
        const float bias = bih[n] + bhh[n];
#pragma unroll
        for (int mi = 0; mi < 4; ++mi) {
#pragma unroll
            for (int r = 0; r < 4; ++r) {
                const int m = m0 + wr + mi * 16 + rb + r;
                const int b = m >> 7, t = m & 127;
                xp[((size_t)t * BATCH + b) * GATES + n] = acc[mi][ni][r] + bias;
            }
        }
    }
}

// ---------------- persistent LSTM scan (256 thr, W in LDS) ------------------
__global__ __launch_bounds__(256, 1) void lstm_scan_kernel(
        const float* __restrict__ Whh,   // [GATES][HDIM] fp32
        const float* __restrict__ xp,    // [TSEQ][BATCH][GATES] fp32
        _Float16* __restrict__ hstep,    // [129][HSTEP_ELEMS] slot ring
        int* __restrict__ flags,         // [2][NFLAG_COPY][256][FLAG_STRIDE]
        int flag_base,
        const float* __restrict__ Wih_nx,   // next layer's W_ih fp32 (or null)
        _Float16* __restrict__ wih_out) {   // fp16 dest for folded cvt
    // Drop stale L1/L2 lines from previous launches/replays (once per launch).
    __builtin_amdgcn_fence(__ATOMIC_ACQUIRE, "agent");

    extern __shared__ char smemW[];               // 128KB: [32 rows][2048] fp16, swizzled
    __shared__ float red[2][8 * 16 * RED_ST];

    const int tid  = threadIdx.x;
    const int lane = tid & 63;
    const int wave = tid >> 6;
    const int blk  = blockIdx.x;
    const int h0   = blk * 8;
    const int ln15 = lane & 15;
    const int kl   = (lane >> 4) * 8;
    const int kbase = wave * 512;

    // ---- stage W_hh slice into LDS: rows 0-7=i,8-15=f,16-23=g,24-31=o ----
    for (int r = 0; r < 32; ++r) {
        const float* wrow = Whh + ((size_t)((r >> 3) * HDIM + h0 + (r & 7))) * HDIM;
        const int c = tid * 8;
        float4 f0 = *(const float4*)(wrow + c);
        float4 f1 = *(const float4*)(wrow + c + 4);
        fp16x8 v;
        v[0] = (_Float16)f0.x; v[1] = (_Float16)f0.y; v[2] = (_Float16)f0.z; v[3] = (_Float16)f0.w;
        v[4] = (_Float16)f1.x; v[5] = (_Float16)f1.y; v[6] = (_Float16)f1.z; v[7] = (_Float16)f1.w;
        uint32_t byte = ((uint32_t)(r * 4096 + c * 2)) ^ ((uint32_t)((r & 7) << 4));
        *(fp16x8*)(smemW + byte) = v;
    }

    float c_state = 0.f;
    const int uh = tid & 7, ub = tid >> 3;   // update thread (tid<128): unit, batch

    const uint32_t sw     = (uint32_t)((ln15 & 7) << 4);
    const uint32_t r0base = (uint32_t)ln15 * 4096u;
    const uint32_t r1base = r0base + 16u * 4096u;

    // wave w consumes k-chunk from blocks [64w,64w+64): poll 1 producer/lane,
    // both flag arrays, replica blk&3.
    const int pidx = ((blk & 3) << 8) | (wave << 6) | lane;
    const int* fa = flags + (size_t)pidx * FLAG_STRIDE;
    const int* fb = fa + FB_OFF;

    __syncthreads();

    for (int t = 0; t < TSEQ; ++t) {
        if (t) {   // parallel polls: both loads issued, then one combined check
            const int want = flag_base + t;
            int va, vb;
            do {
                va = __hip_atomic_load(fa, __ATOMIC_RELAXED, __HIP_MEMORY_SCOPE_AGENT);
                vb = __hip_atomic_load(fb, __ATOMIC_RELAXED, __HIP_MEMORY_SCOPE_AGENT);
            } while (va < want || vb < want);
        }
        asm volatile("" ::: "memory");       // no load hoisting above poll
        const _Float16* hsrc = hstep + (size_t)t * HSTEP_ELEMS;

        // h_{t-1} fragments (issued first: their counted vmcnt excludes xp/cvt)
        fp16x8 af[16];
#pragma unroll
        for (int s = 0; s < 16; ++s) {
            const int k = kbase + s * 32 + kl;
            af[s] = *(const fp16x8*)(hsrc + (size_t)k * 16 + ln15 * 8);
        }
        // xp[t] issued now; consumed after the barrier (drained there).
        float xi = 0.f, xf = 0.f, xg = 0.f, xo = 0.f;
        if (tid < 128) {
            const float* xpt = xp + ((size_t)t * BATCH + ub) * GATES + h0 + uh;
            xi = xpt[0];
            xf = xpt[HDIM];
            xg = xpt[2 * HDIM];
            xo = xpt[3 * HDIM];
        }
        // folded cvt loads: TIME-MAJOR chunk (contiguous 8KB/block/step, fully
        // coalesced); issued after xp, drained at the barrier with it.
        const bool docvt = (Wih_nx != nullptr) && (t < 32);
        const size_t chunk = (size_t)t * 65536 + (size_t)blk * 256 + tid;
        float4 cw0, cw1;
        if (docvt) {
            const float* src = Wih_nx + chunk * 8;
            cw0 = *(const float4*)src;
            cw1 = *(const float4*)(src + 4);
        }

        // MFMA: W fragments from LDS, 4 independent chains (even/odd s).
        f32x4 a0e = {0.f,0.f,0.f,0.f}, a0o = {0.f,0.f,0.f,0.f};
        f32x4 a1e = {0.f,0.f,0.f,0.f}, a1o = {0.f,0.f,0.f,0.f};
#pragma unroll
        for (int s = 0; s < 16; s += 2) {
            const uint32_t kb  = (uint32_t)((kbase + s * 32 + kl) * 2);
            const uint32_t kb1 = kb + 64;
            fp16x8 w0e = *(const fp16x8*)(smemW + ((r0base + kb ) ^ sw));
            fp16x8 w1e = *(const fp16x8*)(smemW + ((r1base + kb ) ^ sw));
            fp16x8 w0o = *(const fp16x8*)(smemW + ((r0base + kb1) ^ sw));
            fp16x8 w1o = *(const fp16x8*)(smemW + ((r1base + kb1) ^ sw));
            a0e = __builtin_amdgcn_mfma_f32_16x16x32_f16(af[s],     w0e, a0e, 0, 0, 0);
            a1e = __builtin_amdgcn_mfma_f32_16x16x32_f16(af[s],     w1e, a1e, 0, 0, 0);
            a0o = __builtin_amdgcn_mfma_f32_16x16x32_f16(af[s + 1], w0o, a0o, 0, 0, 0);
            a1o = __builtin_amdgcn_mfma_f32_16x16x32_f16(af[s + 1], w1o, a1o, 0, 0, 0);
        }
        f32x4 acc0 = a0e + a0o;
        f32x4 acc1 = a1e + a1o;
        {
            float* r0 = red[t & 1] + ((wave * 2 + 0) * 16 + ln15) * RED_ST + (lane >> 4) * 4;
            float* r1 = red[t & 1] + ((wave * 2 + 1) * 16 + ln15) * RED_ST + (lane >> 4) * 4;
#pragma unroll
            for (int i = 0; i < 4; ++i) { r0[i] = acc0[i]; r1[i] = acc1[i]; }
        }
        __syncthreads();                     // single per-step barrier (drains xp+cvt)
        asm volatile("" ::: "memory");

        if (tid < 128) {
            const float* redp = red[t & 1];
            float ip = xi, fp_ = xf, gp = xg, op = xo;
#pragma unroll
            for (int w = 0; w < 4; ++w) {
                ip  += redp[((w * 2 + 0) * 16 + uh    ) * RED_ST + ub];
                fp_ += redp[((w * 2 + 0) * 16 + uh + 8) * RED_ST + ub];
                gp  += redp[((w * 2 + 1) * 16 + uh    ) * RED_ST + ub];
                op  += redp[((w * 2 + 1) * 16 + uh + 8) * RED_ST + ub];
            }
            float ig = sigmoidf_(ip), fg = sigmoidf_(fp_), og = sigmoidf_(op);
            float gg = tanhf_(gp);
            c_state = fg * c_state + ig * gg;
            float hv = og * tanhf_(c_state);
            HU cv; cv.f = (_Float16)hv;
            unsigned v  = cv.u;
            unsigned v1 = __shfl_down(v, 1, 64);
            unsigned v2 = __shfl_down(v, 2, 64);
            unsigned v3 = __shfl_down(v, 3, 64);
            if ((tid & 3) == 0) {            // pack 4 units -> 8B write-through store
                unsigned long long pk = (unsigned long long)v
                                      | ((unsigned long long)v1 << 16)
                                      | ((unsigned long long)v2 << 32)
                                      | ((unsigned long long)v3 << 48);
                unsigned long long* dst = (unsigned long long*)
                    (hstep + (size_t)(t + 1) * HSTEP_ELEMS + blk * HSLOT + ub * 8 + uh);
                __hip_atomic_store(dst, pk, __ATOMIC_RELAXED, __HIP_MEMORY_SCOPE_AGENT);
            }
            if (t < TSEQ - 1) {
                asm volatile("s_waitcnt vmcnt(0)" ::: "memory");   // own h stores at L3
                if (lane == 0) {             // wave0 -> fa[blk], wave1 -> fb[blk]
                    int* base = flags + (wave ? FB_OFF : 0);
#pragma unroll
                    for (int c = 0; c < NFLAG_COPY; ++c)
                        __hip_atomic_store(base + (size_t)((c << 8) | blk) * FLAG_STRIDE,
                                           flag_base + t + 1,
                                           __ATOMIC_RELAXED, __HIP_MEMORY_SCOPE_AGENT);
                }
            }
        }
        // folded cvt: convert + store (coalesced 16B stores, contiguous per
        // block). Store drains at a later barrier — off the critical path.
        if (docvt) {
            fp16x8 v;
            v[0] = (_Float16)cw0.x; v[1] = (_Float16)cw0.y;
            v[2] = (_Float16)cw0.z; v[3] = (_Float16)cw0.w;
            v[4] = (_Float16)cw1.x; v[5] = (_Float16)cw1.y;
            v[6] = (_Float16)cw1.z; v[7] = (_Float16)cw1.w;
            *(fp16x8*)(wih_out + chunk * 8) = v;
        }
    }
}

// ---------------- output projection -----------------------------------------
__global__ __launch_bounds__(256) void outproj_kernel(
        const _Float16* __restrict__ hstep, const float* __restrict__ Wout,
        const float* __restrict__ bout, float* __restrict__ out) {
    const int lane = threadIdx.x & 63;
    const int wave = threadIdx.x >> 6;
    const int tok = blockIdx.x * 4 + wave;
    const int b = tok >> 7, t = tok & 127;
    const _Float16* h = hstep + (size_t)(t + 1) * HSTEP_ELEMS + b * 8;
    float acc = 0.f;
#pragma unroll
    for (int c = 0; c < 4; ++c) {
        const int k = c * 512 + lane * 8;
        fp16x8 hv = *(const fp16x8*)(h + (size_t)k * 16);
        const float* w = Wout + k;
#pragma unroll
        for (int i = 0; i < 8; ++i) acc += (float)hv[i] * w[i];
    }
#pragma unroll
    for (int off = 32; off > 0; off >>= 1) acc += __shfl_down(acc, off, 64);
    if (lane == 0) out[tok] = acc + bout[0];
}

// ---------------- launch -----------------------------------------------------
extern "C" void kernel_launch(void* const* d_in, const int* in_sizes, int n_in,
                              void* d_out, int out_size, void* d_ws, size_t ws_size,
                              hipStream_t stream) {
    (void)in_sizes; (void)n_in; (void)out_size; (void)ws_size;
    const float* x       = (const float*)d_in[0];
    const float* Wih[3]  = {(const float*)d_in[1], (const float*)d_in[5], (const float*)d_in[9]};
    const float* Whh[3]  = {(const float*)d_in[2], (const float*)d_in[6], (const float*)d_in[10]};
    const float* bih[3]  = {(const float*)d_in[3], (const float*)d_in[7], (const float*)d_in[11]};
    const float* bhh[3]  = {(const float*)d_in[4], (const float*)d_in[8], (const float*)d_in[12]};
    const float* Wout    = (const float*)d_in[13];
    const float* bout    = (const float*)d_in[14];
    float* out = (float*)d_out;

    char* ws = (char*)d_ws;
    size_t off = 0;
    auto carve = [&](size_t bytes) {
        char* p = ws + off;
        off += (bytes + 255) & ~(size_t)255;
        return p;
    };
    _Float16* wih16 = (_Float16*)carve((size_t)GATES * 2048 * 2);             // 33.5 MB
    float*    xp    = (float*)   carve((size_t)TSEQ * GATES * BATCH * 4);     // 67 MB
    _Float16* xh    = (_Float16*)carve((size_t)NTOK * 128 * 2);               // 0.5 MB
    _Float16* hstep = (_Float16*)carve((size_t)(TSEQ + 1) * HSTEP_ELEMS * 2); // 8.46 MB
    int*      flags = (int*)     carve((size_t)2 * NFLAG_COPY * 256 * FLAG_STRIDE * 4); // 128 KB

    hipFuncSetAttribute((const void*)lstm_scan_kernel,
                        hipFuncAttributeMaxDynamicSharedMemorySize, W_LDS_BYTES);

    // one-time init (captured in graph, re-runs each replay)
    hipMemsetAsync(flags, 0, (size_t)2 * NFLAG_COPY * 256 * FLAG_STRIDE * 4, stream);
    hipMemsetAsync(hstep, 0, HSTEP_ELEMS * 2, stream);   // slot 0 = h_{-1} = 0

    {   // x -> fp16
        int n8 = NTOK * 128 / 8;
        cvt_f32_f16_kernel<<<(n8 + 255) / 256, 256, 0, stream>>>(x, xh, n8);
    }
    {   // W_ih^0 -> fp16 (small, K=128; layers 1-2 are folded into the scans)
        int n8 = GATES * 128 / 8;
        cvt_f32_f16_kernel<<<(n8 + 255) / 256, 256, 0, stream>>>(Wih[0], wih16, n8);
    }

    const int Kl[3] = {128, 2048, 2048};
    for (int l = 0; l < 3; ++l) {
        dim3 ggrid(GATES / 128, NTOK / 128);
        xproj_gemm_kernel<<<ggrid, 256, 0, stream>>>(
            l == 0 ? xh : nullptr, l == 0 ? nullptr : hstep,
            wih16, bih[l], bhh[l], xp, Kl[l]);
        lstm_scan_kernel<<<256, 256, W_LDS_BYTES, stream>>>(
            Whh[l], xp, hstep, flags, l * TSEQ,
            l < 2 ? Wih[l + 1] : nullptr, wih16);
    }
    outproj_kernel<<<NTOK / 4, 256, 0, stream>>>(hstep, Wout, bout, out);
}

// Round 14
// 1803.952 us; speedup vs baseline: 1.0130x; 1.0130x over previous
//
#include <hip/hip_runtime.h>
#include <hip/hip_fp16.h>
#include <cstdint>
#include <cstddef>

// LSTM 3-layer, H=2048, B=16, T=128, I=128, O=1 (fp32 in/out).
// R14 = R12 base + flat-A path:
//  - Scan dual-writes h: ring slot (scan consumption) + flat A2[b][t][2048]
//    (plain 8B store, L2-ack, drains in existing vmcnt(0)). Kills the GEMM's
//    4x A-read amplification (ring gather had b fixed per m-tile: 16B used
//    per 64B line, 64KB row stride). GEMM + outproj now read coalesced flat.
//  - Folded cvt: time-major chunks (R13, coalesced) + pre-poll issue (R12,
//    latency hides under poll wait).
// Base: W_hh in LDS (XOR-swizzled); dual flag arrays + 4 replicas; cached h
// consumer loads; xp after af; 4 MFMA chains; parallel fa/fb poll.

typedef __attribute__((ext_vector_type(8))) _Float16 fp16x8;
typedef __attribute__((ext_vector_type(4))) float    f32x4;

#define HDIM  2048
#define GATES 8192
#define BATCH 16
#define TSEQ  128
#define NTOK  2048
#define RED_ST 17
#define HSLOT 128               // fp16 per kblock row: 16 batch x 8 units
#define HSTEP_ELEMS 32768       // fp16 per step slot (64KB)
#define FLAG_STRIDE 16          // ints: 64B per flag line
#define NFLAG_COPY 4
#define FB_OFF (NFLAG_COPY * 256 * FLAG_STRIDE)   // second flag array (ints)
#define W_LDS_BYTES 131072

union HU { _Float16 f; unsigned short u; };

__device__ __forceinline__ float sigmoidf_(float x) { return 1.f / (1.f + __expf(-x)); }
__device__ __forceinline__ float tanhf_(float x) {
    float e2 = __expf(2.f * x);
    return 1.f - 2.f / (e2 + 1.f);
}

// ---------------- fp32 -> fp16 conversion (8 elems/thread) -------------------
__global__ __launch_bounds__(256) void cvt_f32_f16_kernel(const float* __restrict__ in,
                                                          _Float16* __restrict__ out, int n8) {
    int i = blockIdx.x * 256 + threadIdx.x;
    if (i >= n8) return;
    const float4* p = (const float4*)in + (size_t)i * 2;
    float4 a = p[0], b = p[1];
    fp16x8 v;
    v[0] = (_Float16)a.x; v[1] = (_Float16)a.y; v[2] = (_Float16)a.z; v[3] = (_Float16)a.w;
    v[4] = (_Float16)b.x; v[5] = (_Float16)b.y; v[6] = (_Float16)b.z; v[7] = (_Float16)b.w;
    ((fp16x8*)out)[i] = v;
}

// ---------------- x_proj GEMM ------------------------------------------------
// A: flat [NTOK][K] fp16 (rows m = b*128+t). Output xp[t][b][n] fp32.
__global__ __launch_bounds__(256) void xproj_gemm_kernel(
        const _Float16* __restrict__ A, const _Float16* __restrict__ W,
        const float* __restrict__ bih, const float* __restrict__ bhh,
        float* __restrict__ xp, int K) {
    __shared__ _Float16 As[128 * 64];
    __shared__ _Float16 Bs[128 * 64];
    const int tid  = threadIdx.x;
    const int lane = tid & 63;
    const int wave = tid >> 6;
    const int n0 = blockIdx.x * 128;
    const int m0 = blockIdx.y * 128;
    const int srow = tid >> 3;
    const int scol = (tid & 7) * 8;
    const int wr = (wave >> 1) * 64;
    const int wc = (wave & 1) * 64;
    const int lr = lane & 15;
    const int lk = (lane >> 4) * 8;

    f32x4 acc[4][4] = {};

    const int nk = K >> 6;
    for (int kt = 0; kt < nk; ++kt) {
        if (kt) __syncthreads();
        const int k0 = kt * 64;
#pragma unroll
        for (int cc = 0; cc < 4; ++cc) {
            const int row = cc * 32 + srow;
            const _Float16* ga = A + (size_t)(m0 + row) * K + k0 + scol;
            const _Float16* gb = W + (size_t)(n0 + row) * K + k0 + scol;
            __builtin_amdgcn_global_load_lds(
                (const __attribute__((address_space(1))) void*)ga,
                (__attribute__((address_space(3))) void*)(As + cc * 2048 + wave * 512), 16, 0, 0);
            __builtin_amdgcn_global_load_lds(
                (const __attribute__((address_space(1))) void*)gb,
                (__attribute__((address_space(3))) void*)(Bs + cc * 2048 + wave * 512), 16, 0, 0);
        }
        __syncthreads();
#pragma unroll
        for (int s = 0; s < 2; ++s) {
            fp16x8 af[4], bf[4];
#pragma unroll
            for (int mi = 0; mi < 4; ++mi)
                af[mi] = *(const fp16x8*)(As + (wr + mi * 16 + lr) * 64 + s * 32 + lk);
#pragma unroll
            for (int ni = 0; ni < 4; ++ni)
                bf[ni] = *(const fp16x8*)(Bs + (wc + ni * 16 + lr) * 64 + s * 32 + lk);
#pragma unroll
            for (int mi = 0; mi < 4; ++mi)
#pragma unroll
                for (int ni = 0; ni < 4; ++ni)
                    acc[mi][ni] = __builtin_amdgcn_mfma_f32_16x16x32_f16(
                        af[mi], bf[ni], acc[mi][ni], 0, 0, 0);
        }
    }
    const int rb = (lane >> 4) * 4;
#pragma unroll
    for (int ni = 0; ni < 4; ++ni) {
        const int n = n0 + wc + ni * 16 + lr;
        const float bias = bih[n] + bhh[n];
#pragma unroll
        for (int mi = 0; mi < 4; ++mi) {
#pragma unroll
            for (int r = 0; r < 4; ++r) {
                const int m = m0 + wr + mi * 16 + rb + r;
                const int b = m >> 7, t = m & 127;
                xp[((size_t)t * BATCH + b) * GATES + n] = acc[mi][ni][r] + bias;
            }
        }
    }
}

// ---------------- persistent LSTM scan (256 thr, W in LDS) ------------------
__global__ __launch_bounds__(256, 1) void lstm_scan_kernel(
        const float* __restrict__ Whh,   // [GATES][HDIM] fp32
        const float* __restrict__ xp,    // [TSEQ][BATCH][GATES] fp32
        _Float16* __restrict__ hstep,    // [129][HSTEP_ELEMS] slot ring
        int* __restrict__ flags,         // [2][NFLAG_COPY][256][FLAG_STRIDE]
        int flag_base,
        const float* __restrict__ Wih_nx,   // next layer's W_ih fp32 (or null)
        _Float16* __restrict__ wih_out,     // fp16 dest for folded cvt
        _Float16* __restrict__ a2out) {     // flat h out: [BATCH][TSEQ][HDIM]
    // Drop stale L1/L2 lines from previous launches/replays (once per launch).
    __builtin_amdgcn_fence(__ATOMIC_ACQUIRE, "agent");

    extern __shared__ char smemW[];               // 128KB: [32 rows][2048] fp16, swizzled
    __shared__ float red[2][8 * 16 * RED_ST];

    const int tid  = threadIdx.x;
    const int lane = tid & 63;
    const int wave = tid >> 6;
    const int blk  = blockIdx.x;
    const int h0   = blk * 8;
    const int ln15 = lane & 15;
    const int kl   = (lane >> 4) * 8;
    const int kbase = wave * 512;

    // ---- stage W_hh slice into LDS: rows 0-7=i,8-15=f,16-23=g,24-31=o ----
    for (int r = 0; r < 32; ++r) {
        const float* wrow = Whh + ((size_t)((r >> 3) * HDIM + h0 + (r & 7))) * HDIM;
        const int c = tid * 8;
        float4 f0 = *(const float4*)(wrow + c);
        float4 f1 = *(const float4*)(wrow + c + 4);
        fp16x8 v;
        v[0] = (_Float16)f0.x; v[1] = (_Float16)f0.y; v[2] = (_Float16)f0.z; v[3] = (_Float16)f0.w;
        v[4] = (_Float16)f1.x; v[5] = (_Float16)f1.y; v[6] = (_Float16)f1.z; v[7] = (_Float16)f1.w;
        uint32_t byte = ((uint32_t)(r * 4096 + c * 2)) ^ ((uint32_t)((r & 7) << 4));
        *(fp16x8*)(smemW + byte) = v;
    }

    float c_state = 0.f;
    const int uh = tid & 7, ub = tid >> 3;   // update thread (tid<128): unit, batch

    const uint32_t sw     = (uint32_t)((ln15 & 7) << 4);
    const uint32_t r0base = (uint32_t)ln15 * 4096u;
    const uint32_t r1base = r0base + 16u * 4096u;

    // wave w consumes k-chunk from blocks [64w,64w+64): poll 1 producer/lane,
    // both flag arrays, replica blk&3.
    const int pidx = ((blk & 3) << 8) | (wave << 6) | lane;
    const int* fa = flags + (size_t)pidx * FLAG_STRIDE;
    const int* fb = fa + FB_OFF;

    __syncthreads();

    for (int t = 0; t < TSEQ; ++t) {
        // folded cvt loads: TIME-MAJOR chunk (contiguous 8KB/block/step),
        // issued BEFORE the poll so HBM latency hides under the poll wait.
        const bool docvt = (Wih_nx != nullptr) && (t < 32);
        const size_t chunk = (size_t)t * 65536 + (size_t)blk * 256 + tid;
        float4 cw0, cw1;
        if (docvt) {
            const float* src = Wih_nx + chunk * 8;
            cw0 = *(const float4*)src;
            cw1 = *(const float4*)(src + 4);
        }

        if (t) {   // parallel polls: both loads issued, then one combined check
            const int want = flag_base + t;
            int va, vb;
            do {
                va = __hip_atomic_load(fa, __ATOMIC_RELAXED, __HIP_MEMORY_SCOPE_AGENT);
                vb = __hip_atomic_load(fb, __ATOMIC_RELAXED, __HIP_MEMORY_SCOPE_AGENT);
            } while (va < want || vb < want);
        }
        asm volatile("" ::: "memory");       // no load hoisting above poll
        const _Float16* hsrc = hstep + (size_t)t * HSTEP_ELEMS;

        // h_{t-1} fragments (issued first: their counted vmcnt excludes xp)
        fp16x8 af[16];
#pragma unroll
        for (int s = 0; s < 16; ++s) {
            const int k = kbase + s * 32 + kl;
            af[s] = *(const fp16x8*)(hsrc + (size_t)k * 16 + ln15 * 8);
        }
        // xp[t] issued now; consumed after the barrier (drained there).
        float xi = 0.f, xf = 0.f, xg = 0.f, xo = 0.f;
        if (tid < 128) {
            const float* xpt = xp + ((size_t)t * BATCH + ub) * GATES + h0 + uh;
            xi = xpt[0];
            xf = xpt[HDIM];
            xg = xpt[2 * HDIM];
            xo = xpt[3 * HDIM];
        }

        // MFMA: W fragments from LDS, 4 independent chains (even/odd s).
        f32x4 a0e = {0.f,0.f,0.f,0.f}, a0o = {0.f,0.f,0.f,0.f};
        f32x4 a1e = {0.f,0.f,0.f,0.f}, a1o = {0.f,0.f,0.f,0.f};
#pragma unroll
        for (int s = 0; s < 16; s += 2) {
            const uint32_t kb  = (uint32_t)((kbase + s * 32 + kl) * 2);
            const uint32_t kb1 = kb + 64;
            fp16x8 w0e = *(const fp16x8*)(smemW + ((r0base + kb ) ^ sw));
            fp16x8 w1e = *(const fp16x8*)(smemW + ((r1base + kb ) ^ sw));
            fp16x8 w0o = *(const fp16x8*)(smemW + ((r0base + kb1) ^ sw));
            fp16x8 w1o = *(const fp16x8*)(smemW + ((r1base + kb1) ^ sw));
            a0e = __builtin_amdgcn_mfma_f32_16x16x32_f16(af[s],     w0e, a0e, 0, 0, 0);
            a1e = __builtin_amdgcn_mfma_f32_16x16x32_f16(af[s],     w1e, a1e, 0, 0, 0);
            a0o = __builtin_amdgcn_mfma_f32_16x16x32_f16(af[s + 1], w0o, a0o, 0, 0, 0);
            a1o = __builtin_amdgcn_mfma_f32_16x16x32_f16(af[s + 1], w1o, a1o, 0, 0, 0);
        }
        f32x4 acc0 = a0e + a0o;
        f32x4 acc1 = a1e + a1o;
        {
            float* r0 = red[t & 1] + ((wave * 2 + 0) * 16 + ln15) * RED_ST + (lane >> 4) * 4;
            float* r1 = red[t & 1] + ((wave * 2 + 1) * 16 + ln15) * RED_ST + (lane >> 4) * 4;
#pragma unroll
            for (int i = 0; i < 4; ++i) { r0[i] = acc0[i]; r1[i] = acc1[i]; }
        }
        __syncthreads();                     // single per-step barrier (drains xp+cvt)
        asm volatile("" ::: "memory");

        if (tid < 128) {
            const float* redp = red[t & 1];
            float ip = xi, fp_ = xf, gp = xg, op = xo;
#pragma unroll
            for (int w = 0; w < 4; ++w) {
                ip  += redp[((w * 2 + 0) * 16 + uh    ) * RED_ST + ub];
                fp_ += redp[((w * 2 + 0) * 16 + uh + 8) * RED_ST + ub];
                gp  += redp[((w * 2 + 1) * 16 + uh    ) * RED_ST + ub];
                op  += redp[((w * 2 + 1) * 16 + uh + 8) * RED_ST + ub];
            }
            float ig = sigmoidf_(ip), fg = sigmoidf_(fp_), og = sigmoidf_(op);
            float gg = tanhf_(gp);
            c_state = fg * c_state + ig * gg;
            float hv = og * tanhf_(c_state);
            HU cv; cv.f = (_Float16)hv;
            unsigned v  = cv.u;
            unsigned v1 = __shfl_down(v, 1, 64);
            unsigned v2 = __shfl_down(v, 2, 64);
            unsigned v3 = __shfl_down(v, 3, 64);
            if ((tid & 3) == 0) {            // pack 4 units -> 8B stores
                unsigned long long pk = (unsigned long long)v
                                      | ((unsigned long long)v1 << 16)
                                      | ((unsigned long long)v2 << 32)
                                      | ((unsigned long long)v3 << 48);
                // ring: write-through agent atomic (scan consumers)
                unsigned long long* dst = (unsigned long long*)
                    (hstep + (size_t)(t + 1) * HSTEP_ELEMS + blk * HSLOT + ub * 8 + uh);
                __hip_atomic_store(dst, pk, __ATOMIC_RELAXED, __HIP_MEMORY_SCOPE_AGENT);
                // flat A2[b][t][hidden]: plain store (L2; visible next kernel)
                unsigned long long* dst2 = (unsigned long long*)
                    (a2out + ((size_t)ub * TSEQ + t) * HDIM + h0 + uh);
                *dst2 = pk;
            }
            if (t < TSEQ - 1) {
                asm volatile("s_waitcnt vmcnt(0)" ::: "memory");   // own h stores at L3
                if (lane == 0) {             // wave0 -> fa[blk], wave1 -> fb[blk]
                    int* base = flags + (wave ? FB_OFF : 0);
#pragma unroll
                    for (int c = 0; c < NFLAG_COPY; ++c)
                        __hip_atomic_store(base + (size_t)((c << 8) | blk) * FLAG_STRIDE,
                                           flag_base + t + 1,
                                           __ATOMIC_RELAXED, __HIP_MEMORY_SCOPE_AGENT);
                }
            }
        }
        // folded cvt: convert + store (coalesced; drains at a later barrier)
        if (docvt) {
            fp16x8 v;
            v[0] = (_Float16)cw0.x; v[1] = (_Float16)cw0.y;
            v[2] = (_Float16)cw0.z; v[3] = (_Float16)cw0.w;
            v[4] = (_Float16)cw1.x; v[5] = (_Float16)cw1.y;
            v[6] = (_Float16)cw1.z; v[7] = (_Float16)cw1.w;
            *(fp16x8*)(wih_out + chunk * 8) = v;
        }
    }
}

// ---------------- output projection (flat h) ---------------------------------
__global__ __launch_bounds__(256) void outproj_kernel(
        const _Float16* __restrict__ a2, const float* __restrict__ Wout,
        const float* __restrict__ bout, float* __restrict__ out) {
    const int lane = threadIdx.x & 63;
    const int wave = threadIdx.x >> 6;
    const int tok = blockIdx.x * 4 + wave;   // tok = b*128 + t
    const _Float16* h = a2 + (size_t)tok * HDIM;
    float acc = 0.f;
#pragma unroll
    for (int c = 0; c < 4; ++c) {
        const int k = c * 512 + lane * 8;
        fp16x8 hv = *(const fp16x8*)(h + k);
        const float* w = Wout + k;
#pragma unroll
        for (int i = 0; i < 8; ++i) acc += (float)hv[i] * w[i];
    }
#pragma unroll
    for (int off = 32; off > 0; off >>= 1) acc += __shfl_down(acc, off, 64);
    if (lane == 0) out[tok] = acc + bout[0];
}

// ---------------- launch -----------------------------------------------------
extern "C" void kernel_launch(void* const* d_in, const int* in_sizes, int n_in,
                              void* d_out, int out_size, void* d_ws, size_t ws_size,
                              hipStream_t stream) {
    (void)in_sizes; (void)n_in; (void)out_size; (void)ws_size;
    const float* x       = (const float*)d_in[0];
    const float* Wih[3]  = {(const float*)d_in[1], (const float*)d_in[5], (const float*)d_in[9]};
    const float* Whh[3]  = {(const float*)d_in[2], (const float*)d_in[6], (const float*)d_in[10]};
    const float* bih[3]  = {(const float*)d_in[3], (const float*)d_in[7], (const float*)d_in[11]};
    const float* bhh[3]  = {(const float*)d_in[4], (const float*)d_in[8], (const float*)d_in[12]};
    const float* Wout    = (const float*)d_in[13];
    const float* bout    = (const float*)d_in[14];
    float* out = (float*)d_out;

    char* ws = (char*)d_ws;
    size_t off = 0;
    auto carve = [&](size_t bytes) {
        char* p = ws + off;
        off += (bytes + 255) & ~(size_t)255;
        return p;
    };
    _Float16* wih16 = (_Float16*)carve((size_t)GATES * 2048 * 2);             // 33.5 MB
    float*    xp    = (float*)   carve((size_t)TSEQ * GATES * BATCH * 4);     // 67 MB
    _Float16* xh    = (_Float16*)carve((size_t)NTOK * 128 * 2);               // 0.5 MB
    _Float16* hstep = (_Float16*)carve((size_t)(TSEQ + 1) * HSTEP_ELEMS * 2); // 8.46 MB
    _Float16* a2    = (_Float16*)carve((size_t)NTOK * HDIM * 2);              // 8.4 MB
    int*      flags = (int*)     carve((size_t)2 * NFLAG_COPY * 256 * FLAG_STRIDE * 4); // 128 KB

    hipFuncSetAttribute((const void*)lstm_scan_kernel,
                        hipFuncAttributeMaxDynamicSharedMemorySize, W_LDS_BYTES);

    // one-time init (captured in graph, re-runs each replay)
    hipMemsetAsync(flags, 0, (size_t)2 * NFLAG_COPY * 256 * FLAG_STRIDE * 4, stream);
    hipMemsetAsync(hstep, 0, HSTEP_ELEMS * 2, stream);   // slot 0 = h_{-1} = 0

    {   // x -> fp16
        int n8 = NTOK * 128 / 8;
        cvt_f32_f16_kernel<<<(n8 + 255) / 256, 256, 0, stream>>>(x, xh, n8);
    }
    {   // W_ih^0 -> fp16 (small, K=128; layers 1-2 are folded into the scans)
        int n8 = GATES * 128 / 8;
        cvt_f32_f16_kernel<<<(n8 + 255) / 256, 256, 0, stream>>>(Wih[0], wih16, n8);
    }

    const int Kl[3] = {128, 2048, 2048};
    for (int l = 0; l < 3; ++l) {
        dim3 ggrid(GATES / 128, NTOK / 128);
        xproj_gemm_kernel<<<ggrid, 256, 0, stream>>>(
            l == 0 ? xh : a2, wih16, bih[l], bhh[l], xp, Kl[l]);
        lstm_scan_kernel<<<256, 256, W_LDS_BYTES, stream>>>(
            Whh[l], xp, hstep, flags, l * TSEQ,
            l < 2 ? Wih[l + 1] : nullptr, wih16, a2);
    }
    outproj_kernel<<<NTOK / 4, 256, 0, stream>>>(a2, Wout, bout, out);
}